// Round 5
// baseline (819.559 us; speedup 1.0000x reference)
//
#include <hip/hip_runtime.h>
#include <hip/hip_bf16.h>
#include <cstdint>

// Problem constants
#define B_ 4
#define T_ 1024
#define W_ 33
#define F_ 512
#define H_ 8
#define DK_ 64

typedef __attribute__((ext_vector_type(8))) short short8;
typedef __attribute__((ext_vector_type(4))) float f32x4;

__device__ __forceinline__ float b2f(ushort u) {
  return __uint_as_float(((uint32_t)u) << 16);
}
__device__ __forceinline__ ushort f2b(float f) {
  union { __hip_bfloat16 b; ushort u; } cv;
  cv.b = __float2bfloat16(f);
  return cv.u;
}

// ---------------------------------------------------------------------------
// Weight convert: W[k][n] f32 -> bf16 in MFMA *fragment order*:
//   dst[((nt*16 + kc)*64 + lane)*8 + e] = W[k][n]
//   with n = nt*16 + (lane&15), k = kc*32 + (lane>>4)*8 + e.
// ---------------------------------------------------------------------------
__global__ void convert_w(const float* __restrict__ Wq, const float* __restrict__ Wk,
                          const float* __restrict__ Wv, const float* __restrict__ Wo,
                          ushort* __restrict__ out)
{
  int which = blockIdx.y;
  const float* src = (which == 0) ? Wq : (which == 1) ? Wk : (which == 2) ? Wv : Wo;
  ushort* dst = out + (size_t)which * 262144;
  int idx = blockIdx.x * 256 + threadIdx.x;     // 0 .. 262143
  int e  = idx & 7;
  int l  = (idx >> 3) & 63;
  int kc = (idx >> 9) & 15;
  int nt = idx >> 13;
  int k = kc * 32 + ((l >> 4) << 3) + e;
  int n = (nt << 4) + (l & 15);
  dst[idx] = f2b(src[k * 512 + n]);
}

// ---------------------------------------------------------------------------
// GEMM: C[M x 512] = A[M x 512] * W[512 x 512] + bias.
// BARRIER-FREE, LDS-FREE: 1-wave output tiles of 64x64. Each wave:
//   - loads A fragments DIRECTLY from global in MFMA layout
//     (lane l: rows m0+mf*16+(l&15), cols ks*32+(l>>4)*8..+8, f32, cvt in reg)
//   - loads B fragments from the fragment-ordered bf16 weight table (L2-hot)
//   - 2-deep software pipeline (A,B prefetched 2 K-steps ahead), 16 MFMA/step
//   - loops over 4 consecutive M-tiles (amortizes prologue/epilogue)
// No __syncthreads anywhere -> waves slip independently; stalls overlap.
// Bijective XCD swizzle: the 2 blocks (8 waves) sharing one A 64-row strip
// are consecutive on one XCD -> A hits that XCD's L2 after first touch.
// Dual-input (blockIdx.y selects) so K-proj and V-proj share one dispatch.
// ---------------------------------------------------------------------------
template<bool A_F32, bool OUT_F32>
__global__ __launch_bounds__(256, 2)
void gemm_kernel(const void* __restrict__ A0p, const void* __restrict__ A1p,
                 const ushort* __restrict__ B0, const ushort* __restrict__ B1,
                 const float* __restrict__ bias0, const float* __restrict__ bias1,
                 void* __restrict__ C0, void* __restrict__ C1)
{
  const int tid  = threadIdx.x;
  const int lane = tid & 63;
  const int wid  = tid >> 6;
  const int lr   = lane & 15;
  const int l8   = (lane >> 4) * 8;

  const void* Ap; const ushort* Bf; const float* bias; void* Cp;
  if (blockIdx.y == 0) { Ap = A0p; Bf = B0; bias = bias0; Cp = C0; }
  else                 { Ap = A1p; Bf = B1; bias = bias1; Cp = C1; }

  // bijective XCD swizzle (m204)
  int nwg  = gridDim.x;
  int xcd  = blockIdx.x & 7;
  int slot = blockIdx.x >> 3;
  int q8   = nwg >> 3, r8 = nwg & 7;
  int base = (xcd < r8) ? xcd * (q8 + 1) : r8 * (q8 + 1) + (xcd - r8) * q8;
  int L    = base + slot;

  const int gw = L * 4 + wid;       // global wave id
  const int ng = gw & 7;            // n-group: cols ng*64 .. +63
  const int mg = gw >> 3;           // m-group: rows mg*256 .. +255
  const int n0 = ng * 64;
  const int ntb = ng * 4;           // base 16-wide n-tile

  float bs[4];
#pragma unroll
  for (int nf = 0; nf < 4; ++nf)
    bs[nf] = bias[n0 + nf * 16 + lr];

  // B fragment base for this wave (lane-resolved); kc-th frag of n-tile nt at
  // Bf[ ((nt*16+kc)*64 + lane)*8 ]
  const ushort* Bfl = Bf + (size_t)lane * 8;

#pragma unroll 1
  for (int mt = 0; mt < 4; ++mt) {
    const int m0 = mg * 256 + mt * 64;

    // lane's A base: row m0+lr, col l8 (f32 or bf16)
    const float*  Af32 = (const float*)Ap + (size_t)(m0 + lr) * 512 + l8;
    const ushort* Ab16 = (const ushort*)Ap + (size_t)(m0 + lr) * 512 + l8;

    f32x4 acc[4][4];
#pragma unroll
    for (int i = 0; i < 4; ++i)
#pragma unroll
      for (int j = 0; j < 4; ++j) acc[i][j] = {0.f, 0.f, 0.f, 0.f};

    float4 p0[8], p1[8];            // A f32 prefetch, 2-deep
    short8 r0_[4], r1_[4];          // A bf16 prefetch (A_F32=false path)
    short8 q0[4], q1[4];            // B prefetch, 2-deep

    auto issueA = [&](int ks, float4 (&P)[8], short8 (&R)[4]) {
#pragma unroll
      for (int mf = 0; mf < 4; ++mf) {
        if (A_F32) {
          const float* s = Af32 + (size_t)mf * 16 * 512 + ks * 32;
          P[mf * 2]     = *(const float4*)s;
          P[mf * 2 + 1] = *(const float4*)(s + 4);
        } else {
          R[mf] = *(const short8*)(Ab16 + (size_t)mf * 16 * 512 + ks * 32);
        }
      }
    };
    auto issueB = [&](int ks, short8 (&Q)[4]) {
#pragma unroll
      for (int nf = 0; nf < 4; ++nf)
        Q[nf] = *(const short8*)(Bfl + (size_t)((ntb + nf) * 16 + ks) * 512);
    };
    auto step = [&](float4 (&P)[8], short8 (&R)[4], short8 (&Q)[4]) {
      short8 ab[4];
#pragma unroll
      for (int mf = 0; mf < 4; ++mf) {
        if (A_F32) {
          float4 u0 = P[mf * 2], u1 = P[mf * 2 + 1];
          short8 hv;
          hv[0] = (short)f2b(u0.x); hv[1] = (short)f2b(u0.y);
          hv[2] = (short)f2b(u0.z); hv[3] = (short)f2b(u0.w);
          hv[4] = (short)f2b(u1.x); hv[5] = (short)f2b(u1.y);
          hv[6] = (short)f2b(u1.z); hv[7] = (short)f2b(u1.w);
          ab[mf] = hv;
        } else {
          ab[mf] = R[mf];
        }
      }
#pragma unroll
      for (int mf = 0; mf < 4; ++mf)
#pragma unroll
        for (int nf = 0; nf < 4; ++nf)
          acc[mf][nf] = __builtin_amdgcn_mfma_f32_16x16x32_bf16(ab[mf], Q[nf], acc[mf][nf], 0, 0, 0);
    };

    // prologue: K-steps 0,1 in flight
    issueA(0, p0, r0_); issueB(0, q0);
    issueA(1, p1, r1_); issueB(1, q1);

#pragma unroll 1
    for (int ks = 0; ks < 16; ks += 2) {
      step(p0, r0_, q0);
      if (ks + 2 < 16) { issueA(ks + 2, p0, r0_); issueB(ks + 2, q0); }
      step(p1, r1_, q1);
      if (ks + 3 < 16) { issueA(ks + 3, p1, r1_); issueB(ks + 3, q1); }
    }

    // epilogue: bias + store (fire-and-forget; overlaps next tile's prologue)
    const int rr = (lane >> 4) * 4;
#pragma unroll
    for (int mf = 0; mf < 4; ++mf) {
#pragma unroll
      for (int nf = 0; nf < 4; ++nf) {
        int gcol = n0 + nf * 16 + lr;
#pragma unroll
        for (int r = 0; r < 4; ++r) {
          int grow = m0 + mf * 16 + rr + r;
          float val = acc[mf][nf][r] + bs[nf];
          if (OUT_F32) ((float*)Cp)[(size_t)grow * 512 + gcol] = val;
          else         ((ushort*)Cp)[(size_t)grow * 512 + gcol] = f2b(val);
        }
      }
    }
  }
}

// ---------------------------------------------------------------------------
// Attention: one block per (b,t). k/v rows for this t staged in LDS.
// ---------------------------------------------------------------------------
__global__ __launch_bounds__(256, 2)
void attn_kernel(const ushort* __restrict__ q, const ushort* __restrict__ k,
                 const ushort* __restrict__ v, const int* __restrict__ mask,
                 ushort* __restrict__ x, int bt0)
{
  __shared__ ushort lk[W_][520];
  __shared__ ushort lv[W_][520];
  __shared__ ushort lq[512];
  __shared__ float  sc[H_][W_];
  __shared__ float  aw[H_][W_];
  __shared__ float  mx[H_], inv[H_];
  __shared__ int    msk[W_];

  const int tid = threadIdx.x;
  const int bt  = blockIdx.x + bt0;        // global b*T + t

  if (tid < 64) ((short8*)lq)[tid] = ((const short8*)(q + (size_t)bt * 512))[tid];
  if (tid < W_) msk[tid] = mask[(size_t)bt * W_ + tid];

  size_t kvbase = (size_t)blockIdx.x * (W_ * 512);
  for (int c = tid; c < W_ * 64; c += 256) {
    int w  = c >> 6;
    int d8 = (c & 63) * 8;
    *(short8*)&lk[w][d8] = *(const short8*)(k + kvbase + w * 512 + d8);
    *(short8*)&lv[w][d8] = *(const short8*)(v + kvbase + w * 512 + d8);
  }
  __syncthreads();

  for (int task = tid; task < H_ * W_; task += 256) {
    int h = task / W_, w = task % W_;
    const ushort* kr = &lk[w][h * 64];
    const ushort* qr = &lq[h * 64];
    float s = 0.f;
#pragma unroll
    for (int d8 = 0; d8 < 8; ++d8) {
      short8 qv = *(const short8*)(qr + d8 * 8);
      short8 kv = *(const short8*)(kr + d8 * 8);
#pragma unroll
      for (int j = 0; j < 8; ++j) s += b2f((ushort)qv[j]) * b2f((ushort)kv[j]);
    }
    s *= 0.125f;
    sc[h][w] = msk[w] ? s : -3.4028234663852886e38f;
  }
  __syncthreads();

  if (tid < H_) {
    float m = -3.4028234663852886e38f;
    for (int w = 0; w < W_; ++w) m = fmaxf(m, sc[tid][w]);
    float ssum = 0.f;
    for (int w = 0; w < W_; ++w) ssum += __expf(sc[tid][w] - m);
    mx[tid] = m;
    inv[tid] = 1.f / ssum;
  }
  __syncthreads();

  for (int task = tid; task < H_ * W_; task += 256) {
    int h = task / W_, w = task % W_;
    aw[h][w] = msk[w] ? __expf(sc[h][w] - mx[h]) * inv[h] : 0.f;
  }
  __syncthreads();

  for (int f = tid; f < 512; f += 256) {
    int h = f >> 6, d = f & 63;
    float a = 0.f;
#pragma unroll
    for (int w = 0; w < W_; ++w) a += aw[h][w] * b2f(lv[w][h * 64 + d]);
    x[(size_t)bt * 512 + f] = f2b(a);
  }
}

// ---------------------------------------------------------------------------
extern "C" void kernel_launch(void* const* d_in, const int* in_sizes, int n_in,
                              void* d_out, int out_size, void* d_ws, size_t ws_size,
                              hipStream_t stream)
{
  const float* query = (const float*)d_in[0];
  const float* key   = (const float*)d_in[1];
  const float* value = (const float*)d_in[2];
  const int*   mask  = (const int*)d_in[3];
  const float* Wq    = (const float*)d_in[4];
  const float* bq    = (const float*)d_in[5];
  const float* Wk    = (const float*)d_in[6];
  const float* bk    = (const float*)d_in[7];
  const float* Wv    = (const float*)d_in[8];
  const float* bv    = (const float*)d_in[9];
  const float* Wo    = (const float*)d_in[10];
  const float* bo    = (const float*)d_in[11];

  char* ws = (char*)d_ws;
  ushort* Wt   = (ushort*)ws;                         // 4 x 512x512 bf16 = 2 MB
  ushort* Wtq  = Wt;
  ushort* Wtk  = Wt + 262144;
  ushort* Wtv  = Wt + 524288;
  ushort* Wto  = Wt + 786432;
  ushort* qws  = (ushort*)(ws + 2 * 1024 * 1024);     // 4 MB
  ushort* xws  = (ushort*)(ws + 6 * 1024 * 1024);     // 4 MB
  ushort* kvws = (ushort*)(ws + 10 * 1024 * 1024);

  // chunk the (b*T) dimension so k/v bf16 intermediates fit in ws.
  // TR multiple of 256 so chunk rows (TR*33) are a multiple of 256.
  size_t fixed = 10ull * 1024 * 1024;
  size_t avail = ws_size > fixed ? ws_size - fixed : 0;
  long trl = (long)(avail / (2ull * W_ * 512 * 2));   // t-rows that fit
  int TR = (int)(trl / 256) * 256;
  if (TR > B_ * T_) TR = B_ * T_;
  if (TR < 256) TR = 256;
  ushort* kws = kvws;
  ushort* vws = kvws + (size_t)TR * W_ * 512;

  convert_w<<<dim3(1024, 4), 256, 0, stream>>>(Wq, Wk, Wv, Wo, Wt);

  // Q projection: M=4096 rows -> grid 4096/128 = 32 blocks
  gemm_kernel<true, false><<<dim3(32, 1), 256, 0, stream>>>(
      query, query, Wtq, Wtq, bq, bq, qws, qws);

  for (int bt0 = 0; bt0 < B_ * T_; bt0 += TR) {
    int rows = B_ * T_ - bt0; if (rows > TR) rows = TR;
    int Mrows = rows * W_;                 // multiple of 256
    const float* kptr = key   + (size_t)bt0 * W_ * 512;
    const float* vptr = value + (size_t)bt0 * W_ * 512;
    // K-proj and V-proj merged into one dispatch (blockIdx.y selects)
    gemm_kernel<true, false><<<dim3(Mrows / 128, 2), 256, 0, stream>>>(
        kptr, vptr, Wtk, Wtv, bk, bv, kws, vws);
    attn_kernel<<<rows, 256, 0, stream>>>(qws, kws, vws, mask, xws, bt0);
  }

  // output projection: x @ Wo + bo -> f32 d_out
  gemm_kernel<false, true><<<dim3(32, 1), 256, 0, stream>>>(
      xws, xws, Wto, Wto, bo, bo, d_out, d_out);
}